// Round 14
// baseline (126.782 us; speedup 1.0000x reference)
//
#include <hip/hip_runtime.h>

#define N_ 2048
#define BN 16384
#define IN_DIM 320
#define QKV_N 1536
// (1/sqrt(320)) * log2(e): folded into Q so QK^T scores are base-2 exponents
#define ALPHA 0.08064911f

typedef float f32x4 __attribute__((ext_vector_type(4)));
typedef short v8s __attribute__((ext_vector_type(8)));
typedef unsigned int u32x2 __attribute__((ext_vector_type(2)));

__device__ __forceinline__ short f2b(float f) {
  unsigned u = __builtin_bit_cast(unsigned, f);
  u = u + 0x7fff + ((u >> 16) & 1);
  return (short)(u >> 16);
}

// pi permutation of kv within a 64-tile (matches S^T lane layout -> PV A-frag slots)
__device__ __forceinline__ int piperm(int t) {
  return ((t >> 5) & 1) * 32 + ((t >> 2) & 3) * 8 + ((t >> 4) & 1) * 4 + (t & 3);
}

// ---------------- Kernel 1: build x = [data | mask | time-embedding] ----------------
__global__ void build_x(const float* __restrict__ times, const float* __restrict__ data,
                        const float* __restrict__ maskv, const float* __restrict__ w_per,
                        const float* __restrict__ b_per, const float* __restrict__ w_lin,
                        const float* __restrict__ b_lin, short* __restrict__ x) {
  int row = blockIdx.x;       // 0..16383
  int t = threadIdx.x;        // 128 threads
  float tt = times[row];
  short* xr = x + (size_t)row * IN_DIM;
  const float* dr = data + (size_t)row * 96;
  const float* mr = maskv + (size_t)row * 96;
  if (t < 96) { xr[t] = f2b(dr[t]); xr[96 + t] = f2b(mr[t]); }
  float val;
  if (t == 0) val = tt * w_lin[0] + b_lin[0];
  else        val = __sinf(tt * w_per[t - 1] + b_per[t - 1]);
  xr[192 + t] = f2b(val);
}

// ---------------- Kernel 1b: per-batch mask prefix scan + compact flags ----------------
__global__ void scan_mask(const int* __restrict__ exist, int* __restrict__ prefix,
                          int* __restrict__ ntg, int* __restrict__ totals,
                          short* __restrict__ flagsc) {
  __shared__ int sums[256];
  int b = blockIdx.x;    // 0..7
  int t = threadIdx.x;   // 0..255
  const int* e = exist + b * 2048;
  int loc[8];
  int s = 0;
#pragma unroll
  for (int j = 0; j < 8; ++j) { loc[j] = s; s += (e[t * 8 + j] != 0) ? 1 : 0; }
  sums[t] = s;
  __syncthreads();
  for (int d = 1; d < 256; d <<= 1) {
    int v = (t >= d) ? sums[t - d] : 0;
    __syncthreads();
    sums[t] += v;
    __syncthreads();
  }
  int total = sums[255];
  int base = (t == 0) ? 0 : sums[t - 1];
#pragma unroll
  for (int j = 0; j < 8; ++j) prefix[b * 2048 + t * 8 + j] = base + loc[j];
  if (t == 0) { ntg[b] = (total + 63) >> 6; totals[b] = total; }
#pragma unroll
  for (int j = 0; j < 8; ++j) {
    int slot = t * 8 + j;
    flagsc[b * 2048 + (slot & ~63) + piperm(slot & 63)] =
        (slot < total) ? (short)0x3F80 : (short)0;
  }
}

// ---------------- Kernel 1c: zero the pad rows of compacted row-major K ------
__global__ void zero_pad(const int* __restrict__ ntg, const int* __restrict__ totals,
                         short* __restrict__ kc) {
  int bh = blockIdx.x;   // 0..63
  int b = bh >> 3;
  int nt = ntg[b], total = totals[b];
  int pad = nt * 64 - total;   // 0..63 rows
  int t = threadIdx.x;         // 512 threads
  v8s z = {0, 0, 0, 0, 0, 0, 0, 0};
  for (int i = t; i < pad * 8; i += 512)
    *(v8s*)&kc[((size_t)bh * N_ + total) * 64 + i * 8] = z;
}

// ---------------- Kernel 2: transpose weights (fp32 -> bf16) ----------------
__global__ void transpose_w(const float* __restrict__ Wq, const float* __restrict__ Wk,
                            const float* __restrict__ Wv, const float* __restrict__ Wfc,
                            short* __restrict__ Wt, short* __restrict__ WfcT) {
  int idx = blockIdx.x * 256 + threadIdx.x;
  if (idx < QKV_N * IN_DIM) {
    int n = idx / IN_DIM, kk = idx - n * IN_DIM;
    const float* W = (n < 512) ? Wq : (n < 1024 ? Wk : Wv);
    Wt[idx] = f2b(W[(size_t)kk * 512 + (n & 511)]);
  } else {
    int j = idx - QKV_N * IN_DIM;   // 0..32767
    int d = j >> 9, kk = j & 511;
    WfcT[j] = f2b(Wfc[kk * 64 + d]);
  }
}

// ---------------- Kernel 3: QKV GEMM (M=16384, N=1536, K=320) ----------------
// q -> [bh][n][d]; K/V -> compacted ROW-MAJOR [bh][dst][d] (dst = prefix[token])
__launch_bounds__(256)
__global__ void qkv_gemm(const short* __restrict__ x, const short* __restrict__ Wt,
                         const float* __restrict__ bq, const float* __restrict__ bk,
                         const float* __restrict__ bv, const int* __restrict__ exist,
                         const int* __restrict__ prefix,
                         short* __restrict__ q, short* __restrict__ kc, short* __restrict__ vc) {
  __shared__ short As[128][40];
  __shared__ short Bs[128][40];
  int bm = blockIdx.x;   // 0..127
  int bn = blockIdx.y;   // 0..11
  int tid = threadIdx.x, wave = tid >> 6, lane = tid & 63;
  int wm = wave >> 1, wn = wave & 1;
  int l16 = lane & 15, lh = lane >> 4;
  f32x4 acc[4][4] = {};
  for (int kt = 0; kt < 10; ++kt) {
    int k0 = kt * 32;
#pragma unroll
    for (int s = 0; s < 2; ++s) {
      int c = tid + s * 256;          // 512 16B-chunks
      int r = c >> 2, c8 = c & 3;
      *(v8s*)&As[r][c8 * 8] = *(const v8s*)&x[(size_t)(bm * 128 + r) * IN_DIM + k0 + c8 * 8];
      *(v8s*)&Bs[r][c8 * 8] = *(const v8s*)&Wt[(size_t)(bn * 128 + r) * IN_DIM + k0 + c8 * 8];
    }
    __syncthreads();
    v8s af[4], bfr[4];
#pragma unroll
    for (int m = 0; m < 4; ++m) af[m] = *(const v8s*)&As[wm * 64 + m * 16 + l16][lh * 8];
#pragma unroll
    for (int n = 0; n < 4; ++n) bfr[n] = *(const v8s*)&Bs[wn * 64 + n * 16 + l16][lh * 8];
#pragma unroll
    for (int m = 0; m < 4; ++m)
#pragma unroll
      for (int n = 0; n < 4; ++n)
        acc[m][n] = __builtin_amdgcn_mfma_f32_16x16x32_bf16(af[m], bfr[n], acc[m][n], 0, 0, 0);
    __syncthreads();
  }
  int w = bn >> 2;   // 0:q 1:k 2:v (uniform per block)
  if (w == 0) {
#pragma unroll
    for (int m = 0; m < 4; ++m) {
      int row0 = bm * 128 + wm * 64 + m * 16 + lh * 4;
#pragma unroll
      for (int n = 0; n < 4; ++n) {
        int c = (bn * 128 + wn * 64 + n * 16 + l16) & 511;
        float bb = bq[c];
        int h = c >> 6, d = c & 63;
#pragma unroll
        for (int r = 0; r < 4; ++r) {
          int rr = row0 + r;
          int b = rr >> 11, ntok = rr & 2047;
          q[(((size_t)(b * 8 + h) * N_ + ntok) << 6) + d] = f2b((acc[m][n][r] + bb) * ALPHA);
        }
      }
    }
  } else {
    short* dbuf = (w == 1) ? kc : vc;
    const float* bias = (w == 1) ? bk : bv;
#pragma unroll
    for (int m = 0; m < 4; ++m) {
      int row0 = bm * 128 + wm * 64 + m * 16 + lh * 4;
      int exr[4], dstr[4];
#pragma unroll
      for (int r = 0; r < 4; ++r) { exr[r] = exist[row0 + r]; dstr[r] = prefix[row0 + r]; }
      int b = row0 >> 11;
#pragma unroll
      for (int n = 0; n < 4; ++n) {
        int c = (bn * 128 + wn * 64 + n * 16 + l16) & 511;
        float bb = bias[c];
        int h = c >> 6, d = c & 63;
#pragma unroll
        for (int r = 0; r < 4; ++r)
          if (exr[r])
            dbuf[(((size_t)(b * 8 + h) * N_ + dstr[r]) << 6) + d] = f2b(acc[m][n][r] + bb);
      }
    }
  }
}

// ---------------- Kernel 3b: V row-major -> fragment-major V' (pi-permuted, padded) ----
__launch_bounds__(256)
__global__ void fragmentize(const short* __restrict__ vc, const int* __restrict__ ntg,
                            const int* __restrict__ totals, short* __restrict__ vT) {
  __shared__ short Vs[64][66];   // +2 pad: 33-word row stride spreads banks
  int bh = blockIdx.x;           // 0..63
  int b = bh >> 3;
  int nt = ntg[b], total = totals[b];
  int tid = threadIdx.x;
  const short* vcp = vc + (size_t)bh * N_ * 64;
  short* vtp = vT + (size_t)bh * 131072;
  for (int tile = blockIdx.y; tile < nt; tile += 4) {
    int base = tile * 64;
#pragma unroll
    for (int s = 0; s < 2; ++s) {
      int c = tid + s * 256, r = c >> 3, c8 = c & 7;
      v8s val = {0, 0, 0, 0, 0, 0, 0, 0};
      if (base + r < total) val = *(const v8s*)&vcp[(size_t)(base + r) * 64 + c8 * 8];
      *(v8s*)&Vs[r][c8 * 8] = val;
    }
    __syncthreads();
#pragma unroll
    for (int s = 0; s < 2; ++s) {
      int c = tid + s * 256;
      int l16 = c & 15, lh = (c >> 4) & 3, kc2 = (c >> 6) & 1, n2 = c >> 7;
      int d = n2 * 16 + l16;
      v8s o;
#pragma unroll
      for (int jj = 0; jj < 8; ++jj) {
        int t2 = kc2 * 32 + (jj >> 2) * 16 + lh * 4 + (jj & 3);
        o[jj] = Vs[t2][d];
      }
      *(v8s*)&vtp[(size_t)tile * 4096 + c * 8] = o;
    }
    __syncthreads();
  }
}

// --- Kernel 4: LDS-free flash attention, 64 q/wave, compacted kv; K read row-major ---
__launch_bounds__(256, 2)
__global__ void attn_kernel(const short* __restrict__ q, const short* __restrict__ kc,
                            const short* __restrict__ vT, const short* __restrict__ flagsc,
                            const int* __restrict__ ntg, const int* __restrict__ exist,
                            short* __restrict__ att) {
  // XCD swizzle: all 8 q-blocks of one (b,h) land on the same XCD (id mod 8)
  int bx = blockIdx.x;                      // 0..511
  int bh = ((bx >> 6) << 3) | (bx & 7);     // 0..63
  int qblk = (bx >> 3) & 7;
  int b = bh >> 3, h = bh & 7;
  int tid = threadIdx.x, wave = tid >> 6, lane = tid & 63;
  int l16 = lane & 15, lh = lane >> 4;
  int q0 = qblk * 256 + wave * 64;
  int nt = ntg[b];
  const short* qp = q + (size_t)bh * N_ * 64;
  const short* kcp = kc + (size_t)bh * N_ * 64;   // row-major compacted; tile stride 4096
  const short* vpt = vT + (size_t)bh * 131072;
  const short* fpt = flagsc + b * N_;
  const int* ex = exist + b * N_;
  v8s qf[4][2];
#pragma unroll
  for (int m = 0; m < 4; ++m)
#pragma unroll
    for (int kcx = 0; kcx < 2; ++kcx)
      qf[m][kcx] = *(const v8s*)&qp[(size_t)(q0 + m * 16 + l16) * 64 + kcx * 32 + lh * 8];
  f32x4 oacc[4][4] = {};
  f32x4 lacc[4] = {};
  const f32x4 zf = {0.f, 0.f, 0.f, 0.f};
  int voff = lane * 8;                      // V': lane*16B
  int vok = l16 * 64 + lh * 8;              // K: row l16, d-chunk lh
  v8s kf[8], vf[8], ff[2];
#pragma unroll
  for (int i = 0; i < 8; ++i) {
    kf[i] = *(const v8s*)&kcp[(i >> 1) * 1024 + (i & 1) * 32 + vok];
    vf[i] = *(const v8s*)&vpt[i * 512 + voff];
  }
  ff[0] = *(const v8s*)&fpt[lh * 8];
  ff[1] = *(const v8s*)&fpt[32 + lh * 8];
#pragma unroll 1
  for (int kt = 0; kt < nt; ++kt) {
    const short* kn = kcp + (size_t)(kt + 1) * 4096;
    const short* vn = vpt + (size_t)(kt + 1) * 4096;
    const short* fn = fpt + (kt + 1) * 64;
    bool pre = (kt + 1 < nt);
    // ---- process m-halves serially to cap register pressure ----
#pragma unroll
    for (int mh = 0; mh < 2; ++mh) {
      // S^T = K @ Q for 2 m's (base-2 exponents; lane: q=l16, kv=n*16+lh*4+r)
      f32x4 sacc[2][4];
#pragma unroll
      for (int n = 0; n < 4; ++n)
#pragma unroll
        for (int mm = 0; mm < 2; ++mm) {
          sacc[mm][n] = __builtin_amdgcn_mfma_f32_16x16x32_bf16(kf[n * 2], qf[mh * 2 + mm][0], zf, 0, 0, 0);
          sacc[mm][n] = __builtin_amdgcn_mfma_f32_16x16x32_bf16(kf[n * 2 + 1], qf[mh * 2 + mm][1], sacc[mm][n], 0, 0, 0);
        }
      // after the last kf use (mh==1 QKT), reload K fragments for next tile
      if (mh == 1 && pre)
#pragma unroll
        for (int i = 0; i < 8; ++i)
          kf[i] = *(const v8s*)&kn[(i >> 1) * 1024 + (i & 1) * 32 + vok];
      // p = 2^s in-register (raw v_exp_f32) -> PV A-fragments
      v8s pf[2][2];
#pragma unroll
      for (int mm = 0; mm < 2; ++mm)
#pragma unroll
        for (int kcx = 0; kcx < 2; ++kcx)
#pragma unroll
          for (int half = 0; half < 2; ++half) {
            int n = kcx * 2 + half;
            float p0 = __builtin_amdgcn_exp2f(sacc[mm][n][0]);
            float p1 = __builtin_amdgcn_exp2f(sacc[mm][n][1]);
            float p2 = __builtin_amdgcn_exp2f(sacc[mm][n][2]);
            float p3 = __builtin_amdgcn_exp2f(sacc[mm][n][3]);
            uint w0, w1;
            asm("v_cvt_pk_bf16_f32 %0, %1, %2" : "=v"(w0) : "v"(p0), "v"(p1));
            asm("v_cvt_pk_bf16_f32 %0, %1, %2" : "=v"(w1) : "v"(p2), "v"(p3));
            ((uint*)&pf[mm][kcx])[half * 2]     = w0;
            ((uint*)&pf[mm][kcx])[half * 2 + 1] = w1;
          }
      // O += P @ V ; l += P @ flag
#pragma unroll
      for (int kcx = 0; kcx < 2; ++kcx) {
#pragma unroll
        for (int mm = 0; mm < 2; ++mm)
          lacc[mh * 2 + mm] = __builtin_amdgcn_mfma_f32_16x16x32_bf16(pf[mm][kcx], ff[kcx], lacc[mh * 2 + mm], 0, 0, 0);
#pragma unroll
        for (int n = 0; n < 4; ++n)
#pragma unroll
          for (int mm = 0; mm < 2; ++mm)
            oacc[mh * 2 + mm][n] = __builtin_amdgcn_mfma_f32_16x16x32_bf16(pf[mm][kcx], vf[n * 2 + kcx], oacc[mh * 2 + mm][n], 0, 0, 0);
      }
    }
    // reload V + flag fragments for next tile (after last vf/ff use)
    if (pre) {
#pragma unroll
      for (int i = 0; i < 8; ++i) vf[i] = *(const v8s*)&vn[i * 512 + voff];
      ff[0] = *(const v8s*)&fn[lh * 8];
      ff[1] = *(const v8s*)&fn[32 + lh * 8];
    }
  }
  // ---- epilogue: normalize, query-mask, write att[b][n][h*64+d] ----
#pragma unroll
  for (int m = 0; m < 4; ++m)
#pragma unroll
    for (int r = 0; r < 4; ++r) {
      int row = q0 + m * 16 + lh * 4 + r;
      float qm = (ex[row] != 0) ? 1.f : 0.f;
      float inv = qm / fmaxf(lacc[m][r], 1e-20f);
#pragma unroll
      for (int n = 0; n < 4; ++n)
        att[((size_t)(b * N_ + row)) * 512 + h * 64 + n * 16 + l16] = f2b(oacc[m][n][r] * inv);
    }
}

// ---------------- Kernel 5: out = att @ Wfc + bfc (M=16384, N=64, K=512), fp32 out ----------
__launch_bounds__(256)
__global__ void out_gemm(const short* __restrict__ att, const short* __restrict__ WfcT,
                         const float* __restrict__ bfc, float* __restrict__ out) {
  __shared__ short As[128][40];
  __shared__ short Bs[64][40];
  int bm = blockIdx.x;
  int tid = threadIdx.x, wave = tid >> 6, lane = tid & 63;
  int l16 = lane & 15, lh = lane >> 4;
  f32x4 acc[2][4] = {};
  for (int kt = 0; kt < 16; ++kt) {
    int k0 = kt * 32;
#pragma unroll
    for (int s = 0; s < 2; ++s) {
      int c = tid + s * 256;
      int r = c >> 2, c8 = c & 3;
      *(v8s*)&As[r][c8 * 8] = *(const v8s*)&att[(size_t)(bm * 128 + r) * 512 + k0 + c8 * 8];
    }
    { int r = tid >> 2, c8 = tid & 3;
      if (r < 64) *(v8s*)&Bs[r][c8 * 8] = *(const v8s*)&WfcT[(size_t)r * 512 + k0 + c8 * 8]; }
    __syncthreads();
    v8s bfr[4];
#pragma unroll
    for (int n = 0; n < 4; ++n) bfr[n] = *(const v8s*)&Bs[n * 16 + l16][lh * 8];
#pragma unroll
    for (int m = 0; m < 2; ++m) {
      v8s af = *(const v8s*)&As[wave * 32 + m * 16 + l16][lh * 8];
#pragma unroll
      for (int n = 0; n < 4; ++n)
        acc[m][n] = __builtin_amdgcn_mfma_f32_16x16x32_bf16(af, bfr[n], acc[m][n], 0, 0, 0);
    }
    __syncthreads();
  }
#pragma unroll
  for (int m = 0; m < 2; ++m)
#pragma unroll
    for (int n = 0; n < 4; ++n) {
      float bb = bfc[n * 16 + l16];
#pragma unroll
      for (int r = 0; r < 4; ++r) {
        int row = bm * 128 + wave * 32 + m * 16 + lh * 4 + r;
        out[(size_t)row * 64 + n * 16 + l16] = acc[m][n][r] + bb;
      }
    }
}

extern "C" void kernel_launch(void* const* d_in, const int* in_sizes, int n_in,
                              void* d_out, int out_size, void* d_ws, size_t ws_size,
                              hipStream_t stream) {
  const float* times = (const float*)d_in[0];
  const float* data  = (const float*)d_in[1];
  const float* maskv = (const float*)d_in[2];
  const int*   exist = (const int*)d_in[3];
  const float* w_per = (const float*)d_in[4];
  const float* b_per = (const float*)d_in[5];
  const float* w_lin = (const float*)d_in[6];
  const float* b_lin = (const float*)d_in[7];
  const float* Wq  = (const float*)d_in[8];
  const float* bq  = (const float*)d_in[9];
  const float* Wk  = (const float*)d_in[10];
  const float* bk  = (const float*)d_in[11];
  const float* Wv  = (const float*)d_in[12];
  const float* bv  = (const float*)d_in[13];
  const float* Wfc = (const float*)d_in[14];
  const float* bfc = (const float*)d_in[15];
  float* out = (float*)d_out;

  char* ws = (char*)d_ws;
  short* x     = (short*)(ws);                    // 16384*320*2  = 10,485,760
  short* Wt    = (short*)(ws + 10485760);         // 1536*320*2   =    983,040
  short* WfcT  = (short*)(ws + 11468800);         // 64*512*2     =     65,536
  short* qb    = (short*)(ws + 11534336);         // 16 MB
  short* kcb   = (short*)(ws + 28311552);         // compacted row-major K, 16 MB
  short* vTb   = (short*)(ws + 45088768);         // fragment-major V', 16 MB
  short* vcb   = (short*)(ws + 61865984);         // compacted row-major V, 16 MB
  short* att   = (short*)(ws + 61865984);         // aliases vcb (vc dead before attn writes)
  short* flagsc= (short*)(ws + 78643200);         // 16384 shorts = 32 KB
  int*   prefix= (int*)(ws + 78675968);           // 16384 ints   = 64 KB
  int*   ntg   = (int*)(ws + 78741504);           // 8 ints
  int*   totals= (int*)(ws + 78741536);           // 8 ints

  build_x<<<BN, 128, 0, stream>>>(times, data, maskv, w_per, b_per, w_lin, b_lin, x);
  scan_mask<<<8, 256, 0, stream>>>(exist, prefix, ntg, totals, flagsc);
  transpose_w<<<2048, 256, 0, stream>>>(Wq, Wk, Wv, Wfc, Wt, WfcT);
  qkv_gemm<<<dim3(128, 12), 256, 0, stream>>>(x, Wt, bq, bk, bv, exist, prefix, qb, kcb, vcb);
  zero_pad<<<64, 512, 0, stream>>>(ntg, totals, kcb);
  fragmentize<<<dim3(64, 4), 256, 0, stream>>>(vcb, ntg, totals, vTb);
  attn_kernel<<<512, 256, 0, stream>>>(qb, kcb, vTb, flagsc, ntg, exist, att);
  out_gemm<<<128, 256, 0, stream>>>(att, WfcT, bfc, out);
}

// Round 15
// 111.634 us; speedup vs baseline: 1.1357x; 1.1357x over previous
//
#include <hip/hip_runtime.h>

#define N_ 2048
#define BN 16384
#define IN_DIM 320
#define QKV_N 1536
// (1/sqrt(320)) * log2(e): folded into Q so QK^T scores are base-2 exponents
#define ALPHA 0.08064911f

typedef float f32x4 __attribute__((ext_vector_type(4)));
typedef short v8s __attribute__((ext_vector_type(8)));
typedef unsigned int u32x2 __attribute__((ext_vector_type(2)));

__device__ __forceinline__ short f2b(float f) {
  unsigned u = __builtin_bit_cast(unsigned, f);
  u = u + 0x7fff + ((u >> 16) & 1);
  return (short)(u >> 16);
}

// pi permutation of kv within a 64-tile (matches S^T lane layout -> PV A-frag slots)
__device__ __forceinline__ int piperm(int t) {
  return ((t >> 5) & 1) * 32 + ((t >> 2) & 3) * 8 + ((t >> 4) & 1) * 4 + (t & 3);
}

// ---------------- Kernel 1: build x = [data | mask | time-embedding] ----------------
__global__ void build_x(const float* __restrict__ times, const float* __restrict__ data,
                        const float* __restrict__ maskv, const float* __restrict__ w_per,
                        const float* __restrict__ b_per, const float* __restrict__ w_lin,
                        const float* __restrict__ b_lin, short* __restrict__ x) {
  int row = blockIdx.x;       // 0..16383
  int t = threadIdx.x;        // 128 threads
  float tt = times[row];
  short* xr = x + (size_t)row * IN_DIM;
  const float* dr = data + (size_t)row * 96;
  const float* mr = maskv + (size_t)row * 96;
  if (t < 96) { xr[t] = f2b(dr[t]); xr[96 + t] = f2b(mr[t]); }
  float val;
  if (t == 0) val = tt * w_lin[0] + b_lin[0];
  else        val = __sinf(tt * w_per[t - 1] + b_per[t - 1]);
  xr[192 + t] = f2b(val);
}

// ---------------- Kernel 1b: per-batch mask prefix scan + compact flags ----------------
__global__ void scan_mask(const int* __restrict__ exist, int* __restrict__ prefix,
                          int* __restrict__ ntg, int* __restrict__ totals,
                          short* __restrict__ flagsc) {
  __shared__ int sums[256];
  int b = blockIdx.x;    // 0..7
  int t = threadIdx.x;   // 0..255
  const int* e = exist + b * 2048;
  int loc[8];
  int s = 0;
#pragma unroll
  for (int j = 0; j < 8; ++j) { loc[j] = s; s += (e[t * 8 + j] != 0) ? 1 : 0; }
  sums[t] = s;
  __syncthreads();
  for (int d = 1; d < 256; d <<= 1) {
    int v = (t >= d) ? sums[t - d] : 0;
    __syncthreads();
    sums[t] += v;
    __syncthreads();
  }
  int total = sums[255];
  int base = (t == 0) ? 0 : sums[t - 1];
#pragma unroll
  for (int j = 0; j < 8; ++j) prefix[b * 2048 + t * 8 + j] = base + loc[j];
  if (t == 0) { ntg[b] = (total + 63) >> 6; totals[b] = total; }
#pragma unroll
  for (int j = 0; j < 8; ++j) {
    int slot = t * 8 + j;
    flagsc[b * 2048 + (slot & ~63) + piperm(slot & 63)] =
        (slot < total) ? (short)0x3F80 : (short)0;
  }
}

// ---------------- Kernel 2: transpose weights (fp32 -> bf16) ----------------
__global__ void transpose_w(const float* __restrict__ Wq, const float* __restrict__ Wk,
                            const float* __restrict__ Wv, const float* __restrict__ Wfc,
                            short* __restrict__ Wt, short* __restrict__ WfcT) {
  int idx = blockIdx.x * 256 + threadIdx.x;
  if (idx < QKV_N * IN_DIM) {
    int n = idx / IN_DIM, kk = idx - n * IN_DIM;
    const float* W = (n < 512) ? Wq : (n < 1024 ? Wk : Wv);
    Wt[idx] = f2b(W[(size_t)kk * 512 + (n & 511)]);
  } else {
    int j = idx - QKV_N * IN_DIM;   // 0..32767
    int d = j >> 9, kk = j & 511;
    WfcT[j] = f2b(Wfc[kk * 64 + d]);
  }
}

// ---------------- Kernel 3: QKV GEMM (M=16384, N=1536, K=320) ----------------
// q -> [bh][n][d]; K/V -> compacted ROW-MAJOR [bh][dst][d] (dst = prefix[token])
__launch_bounds__(256)
__global__ void qkv_gemm(const short* __restrict__ x, const short* __restrict__ Wt,
                         const float* __restrict__ bq, const float* __restrict__ bk,
                         const float* __restrict__ bv, const int* __restrict__ exist,
                         const int* __restrict__ prefix,
                         short* __restrict__ q, short* __restrict__ kc, short* __restrict__ vc) {
  __shared__ short As[128][40];
  __shared__ short Bs[128][40];
  int bm = blockIdx.x;   // 0..127
  int bn = blockIdx.y;   // 0..11
  int tid = threadIdx.x, wave = tid >> 6, lane = tid & 63;
  int wm = wave >> 1, wn = wave & 1;
  int l16 = lane & 15, lh = lane >> 4;
  f32x4 acc[4][4] = {};
  for (int kt = 0; kt < 10; ++kt) {
    int k0 = kt * 32;
#pragma unroll
    for (int s = 0; s < 2; ++s) {
      int c = tid + s * 256;          // 512 16B-chunks
      int r = c >> 2, c8 = c & 3;
      *(v8s*)&As[r][c8 * 8] = *(const v8s*)&x[(size_t)(bm * 128 + r) * IN_DIM + k0 + c8 * 8];
      *(v8s*)&Bs[r][c8 * 8] = *(const v8s*)&Wt[(size_t)(bn * 128 + r) * IN_DIM + k0 + c8 * 8];
    }
    __syncthreads();
    v8s af[4], bfr[4];
#pragma unroll
    for (int m = 0; m < 4; ++m) af[m] = *(const v8s*)&As[wm * 64 + m * 16 + l16][lh * 8];
#pragma unroll
    for (int n = 0; n < 4; ++n) bfr[n] = *(const v8s*)&Bs[wn * 64 + n * 16 + l16][lh * 8];
#pragma unroll
    for (int m = 0; m < 4; ++m)
#pragma unroll
      for (int n = 0; n < 4; ++n)
        acc[m][n] = __builtin_amdgcn_mfma_f32_16x16x32_bf16(af[m], bfr[n], acc[m][n], 0, 0, 0);
    __syncthreads();
  }
  int w = bn >> 2;   // 0:q 1:k 2:v (uniform per block)
  if (w == 0) {
#pragma unroll
    for (int m = 0; m < 4; ++m) {
      int row0 = bm * 128 + wm * 64 + m * 16 + lh * 4;
#pragma unroll
      for (int n = 0; n < 4; ++n) {
        int c = (bn * 128 + wn * 64 + n * 16 + l16) & 511;
        float bb = bq[c];
        int h = c >> 6, d = c & 63;
#pragma unroll
        for (int r = 0; r < 4; ++r) {
          int rr = row0 + r;
          int b = rr >> 11, ntok = rr & 2047;
          q[(((size_t)(b * 8 + h) * N_ + ntok) << 6) + d] = f2b((acc[m][n][r] + bb) * ALPHA);
        }
      }
    }
  } else {
    short* dbuf = (w == 1) ? kc : vc;
    const float* bias = (w == 1) ? bk : bv;
#pragma unroll
    for (int m = 0; m < 4; ++m) {
      int row0 = bm * 128 + wm * 64 + m * 16 + lh * 4;
      int exr[4], dstr[4];
#pragma unroll
      for (int r = 0; r < 4; ++r) { exr[r] = exist[row0 + r]; dstr[r] = prefix[row0 + r]; }
      int b = row0 >> 11;
#pragma unroll
      for (int n = 0; n < 4; ++n) {
        int c = (bn * 128 + wn * 64 + n * 16 + l16) & 511;
        float bb = bias[c];
        int h = c >> 6, d = c & 63;
#pragma unroll
        for (int r = 0; r < 4; ++r)
          if (exr[r])
            dbuf[(((size_t)(b * 8 + h) * N_ + dstr[r]) << 6) + d] = f2b(acc[m][n][r] + bb);
      }
    }
  }
}

// ---- Kernel 3b: IN-PLACE re-layout of compacted K,V tiles to fragment-major ----
// Each 64-token tile occupies the same 4096-short range before/after; stage in LDS,
// barrier, rewrite. Pad rows (>= total) are zeroed here.
__launch_bounds__(256)
__global__ void fragmentize(short* __restrict__ kc, short* __restrict__ vc,
                            const int* __restrict__ ntg, const int* __restrict__ totals) {
  __shared__ short Ks[64][66];
  __shared__ short Vs[64][66];
  int bh = blockIdx.x;           // 0..63
  int b = bh >> 3;
  int nt = ntg[b], total = totals[b];
  int tid = threadIdx.x;
  size_t hb = (size_t)bh * N_ * 64;
  for (int tile = blockIdx.y; tile < nt; tile += 8) {
    int base = tile * 64;
#pragma unroll
    for (int s = 0; s < 2; ++s) {
      int c = tid + s * 256, r = c >> 3, c8 = c & 7;
      v8s kv = {0, 0, 0, 0, 0, 0, 0, 0};
      v8s vv = {0, 0, 0, 0, 0, 0, 0, 0};
      if (base + r < total) {
        kv = *(const v8s*)&kc[hb + (size_t)(base + r) * 64 + c8 * 8];
        vv = *(const v8s*)&vc[hb + (size_t)(base + r) * 64 + c8 * 8];
      }
      *(v8s*)&Ks[r][c8 * 8] = kv;
      *(v8s*)&Vs[r][c8 * 8] = vv;
    }
    __syncthreads();
#pragma unroll
    for (int s = 0; s < 2; ++s) {
      int c = tid + s * 256;
      // K' chunk: i=c>>6 (n*2+kc2), lh2=(c>>4)&3, r16=c&15
      int i = c >> 6, lh2 = (c >> 4) & 3, r16 = c & 15;
      *(v8s*)&kc[hb + (size_t)tile * 4096 + c * 8] =
          *(const v8s*)&Ks[(i >> 1) * 16 + r16][(i & 1) * 32 + lh2 * 8];
      // V' chunk: pi-permuted token gather
      int l16 = c & 15, lh = (c >> 4) & 3, kc2 = (c >> 6) & 1, n2 = c >> 7;
      int d = n2 * 16 + l16;
      v8s o;
#pragma unroll
      for (int jj = 0; jj < 8; ++jj) {
        int t2 = kc2 * 32 + (jj >> 2) * 16 + lh * 4 + (jj & 3);
        o[jj] = Vs[t2][d];
      }
      *(v8s*)&vc[hb + (size_t)tile * 4096 + c * 8] = o;
    }
    __syncthreads();
  }
}

// --- Kernel 4: LDS-free flash attention, 64 q/wave, compacted fragment-major K'/V' ---
__launch_bounds__(256, 2)
__global__ void attn_kernel(const short* __restrict__ q, const short* __restrict__ kT,
                            const short* __restrict__ vT, const short* __restrict__ flagsc,
                            const int* __restrict__ ntg, const int* __restrict__ exist,
                            short* __restrict__ att) {
  // XCD swizzle: all 8 q-blocks of one (b,h) land on the same XCD (id mod 8)
  int bx = blockIdx.x;                      // 0..511
  int bh = ((bx >> 6) << 3) | (bx & 7);     // 0..63
  int qblk = (bx >> 3) & 7;
  int b = bh >> 3, h = bh & 7;
  int tid = threadIdx.x, wave = tid >> 6, lane = tid & 63;
  int l16 = lane & 15, lh = lane >> 4;
  int q0 = qblk * 256 + wave * 64;
  int nt = ntg[b];
  const short* qp = q + (size_t)bh * N_ * 64;
  const short* kpt = kT + (size_t)bh * 131072;
  const short* vpt = vT + (size_t)bh * 131072;
  const short* fpt = flagsc + b * N_;
  const int* ex = exist + b * N_;
  v8s qf[4][2];
#pragma unroll
  for (int m = 0; m < 4; ++m)
#pragma unroll
    for (int kcx = 0; kcx < 2; ++kcx)
      qf[m][kcx] = *(const v8s*)&qp[(size_t)(q0 + m * 16 + l16) * 64 + kcx * 32 + lh * 8];
  f32x4 oacc[4][4] = {};
  f32x4 lacc[4] = {};
  const f32x4 zf = {0.f, 0.f, 0.f, 0.f};
  int voff = lane * 8;                      // lane*16B
  v8s kf[8], vf[8], ff[2];
#pragma unroll
  for (int i = 0; i < 8; ++i) {
    kf[i] = *(const v8s*)&kpt[i * 512 + voff];
    vf[i] = *(const v8s*)&vpt[i * 512 + voff];
  }
  ff[0] = *(const v8s*)&fpt[lh * 8];
  ff[1] = *(const v8s*)&fpt[32 + lh * 8];
#pragma unroll 1
  for (int kt = 0; kt < nt; ++kt) {
    const short* kn = kpt + (size_t)(kt + 1) * 4096;
    const short* vn = vpt + (size_t)(kt + 1) * 4096;
    const short* fn = fpt + (kt + 1) * 64;
    bool pre = (kt + 1 < nt);
    // ---- process m-halves serially to cap register pressure ----
#pragma unroll
    for (int mh = 0; mh < 2; ++mh) {
      // S^T = K @ Q for 2 m's (base-2 exponents; lane: q=l16, kv=n*16+lh*4+r)
      f32x4 sacc[2][4];
#pragma unroll
      for (int n = 0; n < 4; ++n)
#pragma unroll
        for (int mm = 0; mm < 2; ++mm) {
          sacc[mm][n] = __builtin_amdgcn_mfma_f32_16x16x32_bf16(kf[n * 2], qf[mh * 2 + mm][0], zf, 0, 0, 0);
          sacc[mm][n] = __builtin_amdgcn_mfma_f32_16x16x32_bf16(kf[n * 2 + 1], qf[mh * 2 + mm][1], sacc[mm][n], 0, 0, 0);
        }
      // after the last kf use (mh==1 QKT), reload K fragments for next tile
      if (mh == 1 && pre)
#pragma unroll
        for (int i = 0; i < 8; ++i) kf[i] = *(const v8s*)&kn[i * 512 + voff];
      // p = 2^s in-register (raw v_exp_f32) -> PV A-fragments
      v8s pf[2][2];
#pragma unroll
      for (int mm = 0; mm < 2; ++mm)
#pragma unroll
        for (int kcx = 0; kcx < 2; ++kcx)
#pragma unroll
          for (int half = 0; half < 2; ++half) {
            int n = kcx * 2 + half;
            float p0 = __builtin_amdgcn_exp2f(sacc[mm][n][0]);
            float p1 = __builtin_amdgcn_exp2f(sacc[mm][n][1]);
            float p2 = __builtin_amdgcn_exp2f(sacc[mm][n][2]);
            float p3 = __builtin_amdgcn_exp2f(sacc[mm][n][3]);
            uint w0, w1;
            asm("v_cvt_pk_bf16_f32 %0, %1, %2" : "=v"(w0) : "v"(p0), "v"(p1));
            asm("v_cvt_pk_bf16_f32 %0, %1, %2" : "=v"(w1) : "v"(p2), "v"(p3));
            ((uint*)&pf[mm][kcx])[half * 2]     = w0;
            ((uint*)&pf[mm][kcx])[half * 2 + 1] = w1;
          }
      // O += P @ V ; l += P @ flag
#pragma unroll
      for (int kcx = 0; kcx < 2; ++kcx) {
#pragma unroll
        for (int mm = 0; mm < 2; ++mm)
          lacc[mh * 2 + mm] = __builtin_amdgcn_mfma_f32_16x16x32_bf16(pf[mm][kcx], ff[kcx], lacc[mh * 2 + mm], 0, 0, 0);
#pragma unroll
        for (int n = 0; n < 4; ++n)
#pragma unroll
          for (int mm = 0; mm < 2; ++mm)
            oacc[mh * 2 + mm][n] = __builtin_amdgcn_mfma_f32_16x16x32_bf16(pf[mm][kcx], vf[n * 2 + kcx], oacc[mh * 2 + mm][n], 0, 0, 0);
      }
    }
    // reload V + flag fragments for next tile (after last vf/ff use)
    if (pre) {
#pragma unroll
      for (int i = 0; i < 8; ++i) vf[i] = *(const v8s*)&vn[i * 512 + voff];
      ff[0] = *(const v8s*)&fn[lh * 8];
      ff[1] = *(const v8s*)&fn[32 + lh * 8];
    }
  }
  // ---- epilogue: normalize, query-mask, write att[b][n][h*64+d] ----
#pragma unroll
  for (int m = 0; m < 4; ++m)
#pragma unroll
    for (int r = 0; r < 4; ++r) {
      int row = q0 + m * 16 + lh * 4 + r;
      float qm = (ex[row] != 0) ? 1.f : 0.f;
      float inv = qm / fmaxf(lacc[m][r], 1e-20f);
#pragma unroll
      for (int n = 0; n < 4; ++n)
        att[((size_t)(b * N_ + row)) * 512 + h * 64 + n * 16 + l16] = f2b(oacc[m][n][r] * inv);
    }
}

// ---------------- Kernel 5: out = att @ Wfc + bfc (M=16384, N=64, K=512), fp32 out ----------
__launch_bounds__(256)
__global__ void out_gemm(const short* __restrict__ att, const short* __restrict__ WfcT,
                         const float* __restrict__ bfc, float* __restrict__ out) {
  __shared__ short As[128][40];
  __shared__ short Bs[64][40];
  int bm = blockIdx.x;
  int tid = threadIdx.x, wave = tid >> 6, lane = tid & 63;
  int l16 = lane & 15, lh = lane >> 4;
  f32x4 acc[2][4] = {};
  for (int kt = 0; kt < 16; ++kt) {
    int k0 = kt * 32;
#pragma unroll
    for (int s = 0; s < 2; ++s) {
      int c = tid + s * 256;
      int r = c >> 2, c8 = c & 3;
      *(v8s*)&As[r][c8 * 8] = *(const v8s*)&att[(size_t)(bm * 128 + r) * 512 + k0 + c8 * 8];
    }
    { int r = tid >> 2, c8 = tid & 3;
      if (r < 64) *(v8s*)&Bs[r][c8 * 8] = *(const v8s*)&WfcT[(size_t)r * 512 + k0 + c8 * 8]; }
    __syncthreads();
    v8s bfr[4];
#pragma unroll
    for (int n = 0; n < 4; ++n) bfr[n] = *(const v8s*)&Bs[n * 16 + l16][lh * 8];
#pragma unroll
    for (int m = 0; m < 2; ++m) {
      v8s af = *(const v8s*)&As[wave * 32 + m * 16 + l16][lh * 8];
#pragma unroll
      for (int n = 0; n < 4; ++n)
        acc[m][n] = __builtin_amdgcn_mfma_f32_16x16x32_bf16(af, bfr[n], acc[m][n], 0, 0, 0);
    }
    __syncthreads();
  }
#pragma unroll
  for (int m = 0; m < 2; ++m)
#pragma unroll
    for (int n = 0; n < 4; ++n) {
      float bb = bfc[n * 16 + l16];
#pragma unroll
      for (int r = 0; r < 4; ++r) {
        int row = bm * 128 + wave * 32 + m * 16 + lh * 4 + r;
        out[(size_t)row * 64 + n * 16 + l16] = acc[m][n][r] + bb;
      }
    }
}

extern "C" void kernel_launch(void* const* d_in, const int* in_sizes, int n_in,
                              void* d_out, int out_size, void* d_ws, size_t ws_size,
                              hipStream_t stream) {
  const float* times = (const float*)d_in[0];
  const float* data  = (const float*)d_in[1];
  const float* maskv = (const float*)d_in[2];
  const int*   exist = (const int*)d_in[3];
  const float* w_per = (const float*)d_in[4];
  const float* b_per = (const float*)d_in[5];
  const float* w_lin = (const float*)d_in[6];
  const float* b_lin = (const float*)d_in[7];
  const float* Wq  = (const float*)d_in[8];
  const float* bq  = (const float*)d_in[9];
  const float* Wk  = (const float*)d_in[10];
  const float* bk  = (const float*)d_in[11];
  const float* Wv  = (const float*)d_in[12];
  const float* bv  = (const float*)d_in[13];
  const float* Wfc = (const float*)d_in[14];
  const float* bfc = (const float*)d_in[15];
  float* out = (float*)d_out;

  char* ws = (char*)d_ws;
  short* x     = (short*)(ws);                    // 16384*320*2  = 10,485,760
  short* Wt    = (short*)(ws + 10485760);         // 1536*320*2   =    983,040
  short* WfcT  = (short*)(ws + 11468800);         // 64*512*2     =     65,536
  short* qb    = (short*)(ws + 11534336);         // 16 MB
  short* kcb   = (short*)(ws + 28311552);         // compacted K: row-major -> fragment-major (in-place)
  short* vcb   = (short*)(ws + 45088768);         // compacted V: row-major -> fragment-major (in-place)
  short* att   = (short*)(ws + 61865984);         // 16 MB
  short* flagsc= (short*)(ws + 78643200);         // 16384 shorts = 32 KB
  int*   prefix= (int*)(ws + 78675968);           // 16384 ints   = 64 KB
  int*   ntg   = (int*)(ws + 78741504);           // 8 ints
  int*   totals= (int*)(ws + 78741536);           // 8 ints

  build_x<<<BN, 128, 0, stream>>>(times, data, maskv, w_per, b_per, w_lin, b_lin, x);
  scan_mask<<<8, 256, 0, stream>>>(exist, prefix, ntg, totals, flagsc);
  transpose_w<<<2048, 256, 0, stream>>>(Wq, Wk, Wv, Wfc, Wt, WfcT);
  qkv_gemm<<<dim3(128, 12), 256, 0, stream>>>(x, Wt, bq, bk, bv, exist, prefix, qb, kcb, vcb);
  fragmentize<<<dim3(64, 8), 256, 0, stream>>>(kcb, vcb, ntg, totals);
  attn_kernel<<<512, 256, 0, stream>>>(qb, kcb, vcb, flagsc, ntg, exist, att);
  out_gemm<<<128, 256, 0, stream>>>(att, WfcT, bfc, out);
}

// Round 16
// 108.484 us; speedup vs baseline: 1.1687x; 1.0290x over previous
//
#include <hip/hip_runtime.h>

#define N_ 2048
#define BN 16384
#define IN_DIM 320
#define QKV_N 1536
// (1/sqrt(320)) * log2(e): folded into Q so QK^T scores are base-2 exponents
#define ALPHA 0.08064911f

typedef float f32x4 __attribute__((ext_vector_type(4)));
typedef short v8s __attribute__((ext_vector_type(8)));
typedef unsigned int u32x2 __attribute__((ext_vector_type(2)));

__device__ __forceinline__ short f2b(float f) {
  unsigned u = __builtin_bit_cast(unsigned, f);
  u = u + 0x7fff + ((u >> 16) & 1);
  return (short)(u >> 16);
}

__device__ __forceinline__ void gload16(const short* g, void* l) {
  __builtin_amdgcn_global_load_lds((const __attribute__((address_space(1))) void*)g,
                                   (__attribute__((address_space(3))) void*)l, 16, 0, 0);
}

// pi permutation of kv within a 64-tile (matches S^T lane layout -> PV A-frag slots)
__device__ __forceinline__ int piperm(int t) {
  return ((t >> 5) & 1) * 32 + ((t >> 2) & 3) * 8 + ((t >> 4) & 1) * 4 + (t & 3);
}

// ---------------- Kernel 1: build x = [data | mask | time-embedding] ----------------
__global__ void build_x(const float* __restrict__ times, const float* __restrict__ data,
                        const float* __restrict__ maskv, const float* __restrict__ w_per,
                        const float* __restrict__ b_per, const float* __restrict__ w_lin,
                        const float* __restrict__ b_lin, short* __restrict__ x) {
  int row = blockIdx.x;       // 0..16383
  int t = threadIdx.x;        // 128 threads
  float tt = times[row];
  short* xr = x + (size_t)row * IN_DIM;
  const float* dr = data + (size_t)row * 96;
  const float* mr = maskv + (size_t)row * 96;
  if (t < 96) { xr[t] = f2b(dr[t]); xr[96 + t] = f2b(mr[t]); }
  float val;
  if (t == 0) val = tt * w_lin[0] + b_lin[0];
  else        val = __sinf(tt * w_per[t - 1] + b_per[t - 1]);
  xr[192 + t] = f2b(val);
}

// ---------------- Kernel 1b: per-batch mask prefix scan + compact flags ----------------
__global__ void scan_mask(const int* __restrict__ exist, int* __restrict__ prefix,
                          int* __restrict__ ntg, int* __restrict__ totals,
                          short* __restrict__ flagsc) {
  __shared__ int sums[256];
  int b = blockIdx.x;    // 0..7
  int t = threadIdx.x;   // 0..255
  const int* e = exist + b * 2048;
  int loc[8];
  int s = 0;
#pragma unroll
  for (int j = 0; j < 8; ++j) { loc[j] = s; s += (e[t * 8 + j] != 0) ? 1 : 0; }
  sums[t] = s;
  __syncthreads();
  for (int d = 1; d < 256; d <<= 1) {
    int v = (t >= d) ? sums[t - d] : 0;
    __syncthreads();
    sums[t] += v;
    __syncthreads();
  }
  int total = sums[255];
  int base = (t == 0) ? 0 : sums[t - 1];
#pragma unroll
  for (int j = 0; j < 8; ++j) prefix[b * 2048 + t * 8 + j] = base + loc[j];
  if (t == 0) { ntg[b] = (total + 63) >> 6; totals[b] = total; }
#pragma unroll
  for (int j = 0; j < 8; ++j) {
    int slot = t * 8 + j;
    flagsc[b * 2048 + (slot & ~63) + piperm(slot & 63)] =
        (slot < total) ? (short)0x3F80 : (short)0;
  }
}

// ---------------- Kernel 2: transpose weights (fp32 -> bf16) ----------------
__global__ void transpose_w(const float* __restrict__ Wq, const float* __restrict__ Wk,
                            const float* __restrict__ Wv, const float* __restrict__ Wfc,
                            short* __restrict__ Wt, short* __restrict__ WfcT) {
  int idx = blockIdx.x * 256 + threadIdx.x;
  if (idx < QKV_N * IN_DIM) {
    int n = idx / IN_DIM, kk = idx - n * IN_DIM;
    const float* W = (n < 512) ? Wq : (n < 1024 ? Wk : Wv);
    Wt[idx] = f2b(W[(size_t)kk * 512 + (n & 511)]);
  } else {
    int j = idx - QKV_N * IN_DIM;   // 0..32767
    int d = j >> 9, kk = j & 511;
    WfcT[j] = f2b(Wfc[kk * 64 + d]);
  }
}

// ---------------- Kernel 3: QKV GEMM (M=16384, N=1536, K=320) ----------------
// global_load_lds staging, pre-swizzled global source, linear [128][32] LDS tiles.
// q -> [bh][n][d]; K/V -> compacted ROW-MAJOR [bh][dst][d] (dst = prefix[token])
__launch_bounds__(256)
__global__ void qkv_gemm(const short* __restrict__ x, const short* __restrict__ Wt,
                         const float* __restrict__ bq, const float* __restrict__ bk,
                         const float* __restrict__ bv, const int* __restrict__ exist,
                         const int* __restrict__ prefix,
                         short* __restrict__ q, short* __restrict__ kc, short* __restrict__ vc) {
  __shared__ short As[128][32];   // 8 KB, linear rows of 64 B; chunk pos p holds global chunk p^(r&3)
  __shared__ short Bs[128][32];
  int bm = blockIdx.x;   // 0..127
  int bn = blockIdx.y;   // 0..11
  int tid = threadIdx.x, wave = tid >> 6, lane = tid & 63;
  int wm = wave >> 1, wn = wave & 1;
  int l16 = lane & 15, lh = lane >> 4;
  // staging geometry: issue s stages LDS bytes [(wave+4s)*1024, +1024); row=(wave+4s)*16+(lane>>2)
  int srow[2], sgc[2];
#pragma unroll
  for (int s = 0; s < 2; ++s) {
    srow[s] = (wave + 4 * s) * 16 + (lane >> 2);
    sgc[s] = (lane & 3) ^ (srow[s] & 3);      // pre-swizzled global chunk
  }
  const short* xa = x + (size_t)(bm * 128) * IN_DIM;
  const short* wa = Wt + (size_t)(bn * 128) * IN_DIM;
  int rpos = (lh ^ (l16 & 3)) * 8;            // fragment read position (same involution)
  f32x4 acc[4][4] = {};
  for (int kt = 0; kt < 10; ++kt) {
    int k0 = kt * 32;
#pragma unroll
    for (int s = 0; s < 2; ++s) {
      gload16(xa + (size_t)srow[s] * IN_DIM + k0 + sgc[s] * 8,
              (char*)&As[0][0] + (wave + 4 * s) * 1024);
      gload16(wa + (size_t)srow[s] * IN_DIM + k0 + sgc[s] * 8,
              (char*)&Bs[0][0] + (wave + 4 * s) * 1024);
    }
    __syncthreads();   // drains vmcnt -> staged data visible
    v8s af[4], bfr[4];
#pragma unroll
    for (int m = 0; m < 4; ++m) af[m] = *(const v8s*)&As[wm * 64 + m * 16 + l16][rpos];
#pragma unroll
    for (int n = 0; n < 4; ++n) bfr[n] = *(const v8s*)&Bs[wn * 64 + n * 16 + l16][rpos];
#pragma unroll
    for (int m = 0; m < 4; ++m)
#pragma unroll
      for (int n = 0; n < 4; ++n)
        acc[m][n] = __builtin_amdgcn_mfma_f32_16x16x32_bf16(af[m], bfr[n], acc[m][n], 0, 0, 0);
    __syncthreads();
  }
  int w = bn >> 2;   // 0:q 1:k 2:v (uniform per block)
  if (w == 0) {
#pragma unroll
    for (int m = 0; m < 4; ++m) {
      int row0 = bm * 128 + wm * 64 + m * 16 + lh * 4;
#pragma unroll
      for (int n = 0; n < 4; ++n) {
        int c = (bn * 128 + wn * 64 + n * 16 + l16) & 511;
        float bb = bq[c];
        int h = c >> 6, d = c & 63;
#pragma unroll
        for (int r = 0; r < 4; ++r) {
          int rr = row0 + r;
          int b = rr >> 11, ntok = rr & 2047;
          q[(((size_t)(b * 8 + h) * N_ + ntok) << 6) + d] = f2b((acc[m][n][r] + bb) * ALPHA);
        }
      }
    }
  } else {
    short* dbuf = (w == 1) ? kc : vc;
    const float* bias = (w == 1) ? bk : bv;
#pragma unroll
    for (int m = 0; m < 4; ++m) {
      int row0 = bm * 128 + wm * 64 + m * 16 + lh * 4;
      int exr[4], dstr[4];
#pragma unroll
      for (int r = 0; r < 4; ++r) { exr[r] = exist[row0 + r]; dstr[r] = prefix[row0 + r]; }
      int b = row0 >> 11;
#pragma unroll
      for (int n = 0; n < 4; ++n) {
        int c = (bn * 128 + wn * 64 + n * 16 + l16) & 511;
        float bb = bias[c];
        int h = c >> 6, d = c & 63;
#pragma unroll
        for (int r = 0; r < 4; ++r)
          if (exr[r])
            dbuf[(((size_t)(b * 8 + h) * N_ + dstr[r]) << 6) + d] = f2b(acc[m][n][r] + bb);
      }
    }
  }
}

// ---- Kernel 3b: IN-PLACE re-layout of compacted K,V tiles to fragment-major ----
__launch_bounds__(256)
__global__ void fragmentize(short* __restrict__ kc, short* __restrict__ vc,
                            const int* __restrict__ ntg, const int* __restrict__ totals) {
  __shared__ short Ks[64][66];
  __shared__ short Vs[64][66];
  int bh = blockIdx.x;           // 0..63
  int b = bh >> 3;
  int nt = ntg[b], total = totals[b];
  int tid = threadIdx.x;
  size_t hb = (size_t)bh * N_ * 64;
  for (int tile = blockIdx.y; tile < nt; tile += 8) {
    int base = tile * 64;
#pragma unroll
    for (int s = 0; s < 2; ++s) {
      int c = tid + s * 256, r = c >> 3, c8 = c & 7;
      v8s kv = {0, 0, 0, 0, 0, 0, 0, 0};
      v8s vv = {0, 0, 0, 0, 0, 0, 0, 0};
      if (base + r < total) {
        kv = *(const v8s*)&kc[hb + (size_t)(base + r) * 64 + c8 * 8];
        vv = *(const v8s*)&vc[hb + (size_t)(base + r) * 64 + c8 * 8];
      }
      *(v8s*)&Ks[r][c8 * 8] = kv;
      *(v8s*)&Vs[r][c8 * 8] = vv;
    }
    __syncthreads();
#pragma unroll
    for (int s = 0; s < 2; ++s) {
      int c = tid + s * 256;
      // K' chunk: i=c>>6 (n*2+kc2), lh2=(c>>4)&3, r16=c&15
      int i = c >> 6, lh2 = (c >> 4) & 3, r16 = c & 15;
      *(v8s*)&kc[hb + (size_t)tile * 4096 + c * 8] =
          *(const v8s*)&Ks[(i >> 1) * 16 + r16][(i & 1) * 32 + lh2 * 8];
      // V' chunk: pi-permuted token gather
      int l16 = c & 15, lh = (c >> 4) & 3, kc2 = (c >> 6) & 1, n2 = c >> 7;
      int d = n2 * 16 + l16;
      v8s o;
#pragma unroll
      for (int jj = 0; jj < 8; ++jj) {
        int t2 = kc2 * 32 + (jj >> 2) * 16 + lh * 4 + (jj & 3);
        o[jj] = Vs[t2][d];
      }
      *(v8s*)&vc[hb + (size_t)tile * 4096 + c * 8] = o;
    }
    __syncthreads();
  }
}

// --- Kernel 4: LDS-free flash attention, 64 q/wave, compacted fragment-major K'/V' ---
__launch_bounds__(256, 2)
__global__ void attn_kernel(const short* __restrict__ q, const short* __restrict__ kT,
                            const short* __restrict__ vT, const short* __restrict__ flagsc,
                            const int* __restrict__ ntg, const int* __restrict__ exist,
                            short* __restrict__ att) {
  // XCD swizzle: all 8 q-blocks of one (b,h) land on the same XCD (id mod 8)
  int bx = blockIdx.x;                      // 0..511
  int bh = ((bx >> 6) << 3) | (bx & 7);     // 0..63
  int qblk = (bx >> 3) & 7;
  int b = bh >> 3, h = bh & 7;
  int tid = threadIdx.x, wave = tid >> 6, lane = tid & 63;
  int l16 = lane & 15, lh = lane >> 4;
  int q0 = qblk * 256 + wave * 64;
  int nt = ntg[b];
  const short* qp = q + (size_t)bh * N_ * 64;
  const short* kpt = kT + (size_t)bh * 131072;
  const short* vpt = vT + (size_t)bh * 131072;
  const short* fpt = flagsc + b * N_;
  const int* ex = exist + b * N_;
  v8s qf[4][2];
#pragma unroll
  for (int m = 0; m < 4; ++m)
#pragma unroll
    for (int kcx = 0; kcx < 2; ++kcx)
      qf[m][kcx] = *(const v8s*)&qp[(size_t)(q0 + m * 16 + l16) * 64 + kcx * 32 + lh * 8];
  f32x4 oacc[4][4] = {};
  f32x4 lacc[4] = {};
  const f32x4 zf = {0.f, 0.f, 0.f, 0.f};
  int voff = lane * 8;                      // lane*16B
  v8s kf[8], vf[8], ff[2];
#pragma unroll
  for (int i = 0; i < 8; ++i) {
    kf[i] = *(const v8s*)&kpt[i * 512 + voff];
    vf[i] = *(const v8s*)&vpt[i * 512 + voff];
  }
  ff[0] = *(const v8s*)&fpt[lh * 8];
  ff[1] = *(const v8s*)&fpt[32 + lh * 8];
#pragma unroll 1
  for (int kt = 0; kt < nt; ++kt) {
    const short* kn = kpt + (size_t)(kt + 1) * 4096;
    const short* vn = vpt + (size_t)(kt + 1) * 4096;
    const short* fn = fpt + (kt + 1) * 64;
    bool pre = (kt + 1 < nt);
    // ---- process m-halves serially to cap register pressure ----
#pragma unroll
    for (int mh = 0; mh < 2; ++mh) {
      // S^T = K @ Q for 2 m's (base-2 exponents; lane: q=l16, kv=n*16+lh*4+r)
      f32x4 sacc[2][4];
#pragma unroll
      for (int n = 0; n < 4; ++n)
#pragma unroll
        for (int mm = 0; mm < 2; ++mm) {
          sacc[mm][n] = __builtin_amdgcn_mfma_f32_16x16x32_bf16(kf[n * 2], qf[mh * 2 + mm][0], zf, 0, 0, 0);
          sacc[mm][n] = __builtin_amdgcn_mfma_f32_16x16x32_bf16(kf[n * 2 + 1], qf[mh * 2 + mm][1], sacc[mm][n], 0, 0, 0);
        }
      // after the last kf use (mh==1 QKT), reload K fragments for next tile
      if (mh == 1 && pre)
#pragma unroll
        for (int i = 0; i < 8; ++i) kf[i] = *(const v8s*)&kn[i * 512 + voff];
      // p = 2^s in-register (raw v_exp_f32) -> PV A-fragments
      v8s pf[2][2];
#pragma unroll
      for (int mm = 0; mm < 2; ++mm)
#pragma unroll
        for (int kcx = 0; kcx < 2; ++kcx)
#pragma unroll
          for (int half = 0; half < 2; ++half) {
            int n = kcx * 2 + half;
            float p0 = __builtin_amdgcn_exp2f(sacc[mm][n][0]);
            float p1 = __builtin_amdgcn_exp2f(sacc[mm][n][1]);
            float p2 = __builtin_amdgcn_exp2f(sacc[mm][n][2]);
            float p3 = __builtin_amdgcn_exp2f(sacc[mm][n][3]);
            uint w0, w1;
            asm("v_cvt_pk_bf16_f32 %0, %1, %2" : "=v"(w0) : "v"(p0), "v"(p1));
            asm("v_cvt_pk_bf16_f32 %0, %1, %2" : "=v"(w1) : "v"(p2), "v"(p3));
            ((uint*)&pf[mm][kcx])[half * 2]     = w0;
            ((uint*)&pf[mm][kcx])[half * 2 + 1] = w1;
          }
      // O += P @ V ; l += P @ flag
#pragma unroll
      for (int kcx = 0; kcx < 2; ++kcx) {
#pragma unroll
        for (int mm = 0; mm < 2; ++mm)
          lacc[mh * 2 + mm] = __builtin_amdgcn_mfma_f32_16x16x32_bf16(pf[mm][kcx], ff[kcx], lacc[mh * 2 + mm], 0, 0, 0);
#pragma unroll
        for (int n = 0; n < 4; ++n)
#pragma unroll
          for (int mm = 0; mm < 2; ++mm)
            oacc[mh * 2 + mm][n] = __builtin_amdgcn_mfma_f32_16x16x32_bf16(pf[mm][kcx], vf[n * 2 + kcx], oacc[mh * 2 + mm][n], 0, 0, 0);
      }
    }
    // reload V + flag fragments for next tile (after last vf/ff use)
    if (pre) {
#pragma unroll
      for (int i = 0; i < 8; ++i) vf[i] = *(const v8s*)&vn[i * 512 + voff];
      ff[0] = *(const v8s*)&fn[lh * 8];
      ff[1] = *(const v8s*)&fn[32 + lh * 8];
    }
  }
  // ---- epilogue: normalize, query-mask, write att[b][n][h*64+d] ----
#pragma unroll
  for (int m = 0; m < 4; ++m)
#pragma unroll
    for (int r = 0; r < 4; ++r) {
      int row = q0 + m * 16 + lh * 4 + r;
      float qm = (ex[row] != 0) ? 1.f : 0.f;
      float inv = qm / fmaxf(lacc[m][r], 1e-20f);
#pragma unroll
      for (int n = 0; n < 4; ++n)
        att[((size_t)(b * N_ + row)) * 512 + h * 64 + n * 16 + l16] = f2b(oacc[m][n][r] * inv);
    }
}

// ---------------- Kernel 5: out = att @ Wfc + bfc (M=16384, N=64, K=512), fp32 out ----------
__launch_bounds__(256)
__global__ void out_gemm(const short* __restrict__ att, const short* __restrict__ WfcT,
                         const float* __restrict__ bfc, float* __restrict__ out) {
  __shared__ short As[128][40];
  __shared__ short Bs[64][40];
  int bm = blockIdx.x;
  int tid = threadIdx.x, wave = tid >> 6, lane = tid & 63;
  int l16 = lane & 15, lh = lane >> 4;
  f32x4 acc[2][4] = {};
  for (int kt = 0; kt < 16; ++kt) {
    int k0 = kt * 32;
#pragma unroll
    for (int s = 0; s < 2; ++s) {
      int c = tid + s * 256;
      int r = c >> 2, c8 = c & 3;
      *(v8s*)&As[r][c8 * 8] = *(const v8s*)&att[(size_t)(bm * 128 + r) * 512 + k0 + c8 * 8];
    }
    { int r = tid >> 2, c8 = tid & 3;
      if (r < 64) *(v8s*)&Bs[r][c8 * 8] = *(const v8s*)&WfcT[(size_t)r * 512 + k0 + c8 * 8]; }
    __syncthreads();
    v8s bfr[4];
#pragma unroll
    for (int n = 0; n < 4; ++n) bfr[n] = *(const v8s*)&Bs[n * 16 + l16][lh * 8];
#pragma unroll
    for (int m = 0; m < 2; ++m) {
      v8s af = *(const v8s*)&As[wave * 32 + m * 16 + l16][lh * 8];
#pragma unroll
      for (int n = 0; n < 4; ++n)
        acc[m][n] = __builtin_amdgcn_mfma_f32_16x16x32_bf16(af, bfr[n], acc[m][n], 0, 0, 0);
    }
    __syncthreads();
  }
#pragma unroll
  for (int m = 0; m < 2; ++m)
#pragma unroll
    for (int n = 0; n < 4; ++n) {
      float bb = bfc[n * 16 + l16];
#pragma unroll
      for (int r = 0; r < 4; ++r) {
        int row = bm * 128 + wave * 32 + m * 16 + lh * 4 + r;
        out[(size_t)row * 64 + n * 16 + l16] = acc[m][n][r] + bb;
      }
    }
}

extern "C" void kernel_launch(void* const* d_in, const int* in_sizes, int n_in,
                              void* d_out, int out_size, void* d_ws, size_t ws_size,
                              hipStream_t stream) {
  const float* times = (const float*)d_in[0];
  const float* data  = (const float*)d_in[1];
  const float* maskv = (const float*)d_in[2];
  const int*   exist = (const int*)d_in[3];
  const float* w_per = (const float*)d_in[4];
  const float* b_per = (const float*)d_in[5];
  const float* w_lin = (const float*)d_in[6];
  const float* b_lin = (const float*)d_in[7];
  const float* Wq  = (const float*)d_in[8];
  const float* bq  = (const float*)d_in[9];
  const float* Wk  = (const float*)d_in[10];
  const float* bk  = (const float*)d_in[11];
  const float* Wv  = (const float*)d_in[12];
  const float* bv  = (const float*)d_in[13];
  const float* Wfc = (const float*)d_in[14];
  const float* bfc = (const float*)d_in[15];
  float* out = (float*)d_out;

  char* ws = (char*)d_ws;
  short* x     = (short*)(ws);                    // 16384*320*2  = 10,485,760
  short* Wt    = (short*)(ws + 10485760);         // 1536*320*2   =    983,040
  short* WfcT  = (short*)(ws + 11468800);         // 64*512*2     =     65,536
  short* qb    = (short*)(ws + 11534336);         // 16 MB
  short* kcb   = (short*)(ws + 28311552);         // compacted K: row-major -> fragment-major (in-place)
  short* vcb   = (short*)(ws + 45088768);         // compacted V: row-major -> fragment-major (in-place)
  short* att   = (short*)(ws + 61865984);         // 16 MB
  short* flagsc= (short*)(ws + 78643200);         // 16384 shorts = 32 KB
  int*   prefix= (int*)(ws + 78675968);           // 16384 ints   = 64 KB
  int*   ntg   = (int*)(ws + 78741504);           // 8 ints
  int*   totals= (int*)(ws + 78741536);           // 8 ints

  build_x<<<BN, 128, 0, stream>>>(times, data, maskv, w_per, b_per, w_lin, b_lin, x);
  scan_mask<<<8, 256, 0, stream>>>(exist, prefix, ntg, totals, flagsc);
  transpose_w<<<2048, 256, 0, stream>>>(Wq, Wk, Wv, Wfc, Wt, WfcT);
  qkv_gemm<<<dim3(128, 12), 256, 0, stream>>>(x, Wt, bq, bk, bv, exist, prefix, qb, kcb, vcb);
  fragmentize<<<dim3(64, 8), 256, 0, stream>>>(kcb, vcb, ntg, totals);
  attn_kernel<<<512, 256, 0, stream>>>(qb, kcb, vcb, flagsc, ntg, exist, att);
  out_gemm<<<128, 256, 0, stream>>>(att, WfcT, bfc, out);
}